// Round 1
// baseline (146.470 us; speedup 1.0000x reference)
//
#include <hip/hip_runtime.h>
#include <hip/hip_bf16.h>

// Output[b,0,i] = S[b] for all i, where
//   S[b] = sum_j (row[b,j] + b_row) * (col[b,j] + b_col)
//   col[b,i] = sum_j x[b,i,j] * w_col[j]   (weighted row-dot)
//   row[b,j] = sum_i x[b,i,j] * w_row[i]   (weighted column-sum)

#define K 1024
#define NB 128
#define ROWBLOCKS_PER_B 16   // 64 rows per block
#define ROWS_PER_BLOCK 64

__global__ __launch_bounds__(256) void
rowcol_kernel(const float* __restrict__ x,
              const float* __restrict__ w_col,
              const float* __restrict__ w_row,
              float* __restrict__ col_ws,    // [NB][K] raw (no bias)
              float* __restrict__ row_ws)    // [NB][K] raw (no bias), pre-zeroed, atomic accum
{
    const int bid  = blockIdx.x;
    const int b    = bid >> 4;          // / ROWBLOCKS_PER_B
    const int rb   = bid & 15;
    const int row0 = rb * ROWS_PER_BLOCK;
    const int tid  = threadIdx.x;
    const int wave = tid >> 6;
    const int lane = tid & 63;

    const float* xb = x + (size_t)b * K * K;

    // Register-cache this lane's w_col fragment: columns jt*256 + lane*4 .. +3
    float4 wc[4];
#pragma unroll
    for (int jt = 0; jt < 4; ++jt)
        wc[jt] = *reinterpret_cast<const float4*>(w_col + jt * 256 + lane * 4);

    // Per-lane column partials for row[b,j] (this wave's 16 rows only)
    float4 p[4];
#pragma unroll
    for (int jt = 0; jt < 4; ++jt) p[jt] = make_float4(0.f, 0.f, 0.f, 0.f);

    // Each wave handles rows row0 + wave*16 + k, k = 0..15
    for (int k = 0; k < 16; ++k) {
        const int r = row0 + wave * 16 + k;
        const float wr = w_row[r];
        const float* xr = xb + (size_t)r * K;
        float cacc = 0.f;
#pragma unroll
        for (int jt = 0; jt < 4; ++jt) {
            float4 xv = *reinterpret_cast<const float4*>(xr + jt * 256 + lane * 4);
            cacc += xv.x * wc[jt].x + xv.y * wc[jt].y + xv.z * wc[jt].z + xv.w * wc[jt].w;
            p[jt].x += xv.x * wr;
            p[jt].y += xv.y * wr;
            p[jt].z += xv.z * wr;
            p[jt].w += xv.w * wr;
        }
        // 64-lane reduction for the row dot product
#pragma unroll
        for (int off = 32; off; off >>= 1) cacc += __shfl_xor(cacc, off);
        if (lane == 0) col_ws[b * K + r] = cacc;
    }

    // Combine the 4 waves' column partials in LDS, then one atomicAdd per column
    __shared__ float rp[4][K];   // 16 KiB
#pragma unroll
    for (int jt = 0; jt < 4; ++jt)
        *reinterpret_cast<float4*>(&rp[wave][jt * 256 + lane * 4]) = p[jt];
    __syncthreads();

    // thread tid owns columns tid*4 .. tid*4+3
    const int j0 = tid * 4;
    float4 s0 = *reinterpret_cast<const float4*>(&rp[0][j0]);
    float4 s1 = *reinterpret_cast<const float4*>(&rp[1][j0]);
    float4 s2 = *reinterpret_cast<const float4*>(&rp[2][j0]);
    float4 s3 = *reinterpret_cast<const float4*>(&rp[3][j0]);
    float sx = s0.x + s1.x + s2.x + s3.x;
    float sy = s0.y + s1.y + s2.y + s3.y;
    float sz = s0.z + s1.z + s2.z + s3.z;
    float sw = s0.w + s1.w + s2.w + s3.w;
    float* dst = row_ws + b * K + j0;
    atomicAdd(dst + 0, sx);
    atomicAdd(dst + 1, sy);
    atomicAdd(dst + 2, sz);
    atomicAdd(dst + 3, sw);
}

__global__ __launch_bounds__(256) void
finalize_kernel(const float* __restrict__ col_ws,
                const float* __restrict__ row_ws,
                const float* __restrict__ b_col_p,
                const float* __restrict__ b_row_p,
                float* __restrict__ out)
{
    const int b    = blockIdx.x;
    const int tid  = threadIdx.x;
    const int wave = tid >> 6;
    const int lane = tid & 63;
    const float bc = b_col_p[0];
    const float br = b_row_p[0];

    const int j0 = tid * 4;
    float4 c = *reinterpret_cast<const float4*>(&col_ws[b * K + j0]);
    float4 r = *reinterpret_cast<const float4*>(&row_ws[b * K + j0]);
    float acc = (c.x + bc) * (r.x + br)
              + (c.y + bc) * (r.y + br)
              + (c.z + bc) * (r.z + br)
              + (c.w + bc) * (r.w + br);
#pragma unroll
    for (int off = 32; off; off >>= 1) acc += __shfl_xor(acc, off);

    __shared__ float red[4];
    if (lane == 0) red[wave] = acc;
    __syncthreads();
    const float S = red[0] + red[1] + red[2] + red[3];

    float4 o = make_float4(S, S, S, S);
    *reinterpret_cast<float4*>(&out[b * K + j0]) = o;
}

extern "C" void kernel_launch(void* const* d_in, const int* in_sizes, int n_in,
                              void* d_out, int out_size, void* d_ws, size_t ws_size,
                              hipStream_t stream) {
    const float* x     = (const float*)d_in[0];
    const float* w_col = (const float*)d_in[1];
    const float* b_col = (const float*)d_in[2];
    const float* w_row = (const float*)d_in[3];
    const float* b_row = (const float*)d_in[4];
    float* out = (float*)d_out;

    float* col_ws = (float*)d_ws;              // NB*K floats
    float* row_ws = col_ws + (size_t)NB * K;   // NB*K floats, atomic-accumulated

    // row_ws must start at zero every call (atomic accumulation)
    hipMemsetAsync(row_ws, 0, (size_t)NB * K * sizeof(float), stream);

    rowcol_kernel<<<NB * ROWBLOCKS_PER_B, 256, 0, stream>>>(x, w_col, w_row, col_ws, row_ws);
    finalize_kernel<<<NB, 256, 0, stream>>>(col_ws, row_ws, b_col, b_row, out);
}

// Round 2
// 112.702 us; speedup vs baseline: 1.2996x; 1.2996x over previous
//
#include <hip/hip_runtime.h>
#include <hip/hip_bf16.h>

// Output[b,0,i] = S[b] for all i, where
//   S[b] = sum_j (row[b,j] + b_row) * (col[b,j] + b_col)
//   col[b,i] = sum_j x[b,i,j] * w_col[j]   (weighted row-dot)
//   row[b,j] = sum_i x[b,i,j] * w_row[i]   (weighted column-sum)
//
// Kernel 1: 2048 blocks (B=128 x 16 row-blocks of 64 rows). Streams x once
//   (coalesced float4, nontemporal), writes col_ws[b][r] and per-block
//   column partials rowpart[bid][j]  (no atomics, no memset needed).
// Kernel 2: 128 blocks. Sums the 16 partials per b, dots with col, broadcasts.

#define K 1024
#define NB 128

typedef float f32x4 __attribute__((ext_vector_type(4)));

__global__ __launch_bounds__(256) void
rowcol_kernel(const float* __restrict__ x,
              const float* __restrict__ w_col,
              const float* __restrict__ w_row,
              float* __restrict__ col_ws,     // [NB][K] raw (no bias)
              float* __restrict__ rowpart)    // [NB*16][K] per-block partials
{
    const int bid  = blockIdx.x;
    const int b    = bid >> 4;
    const int rb   = bid & 15;
    const int row0 = rb * 64;
    const int tid  = threadIdx.x;
    const int wave = tid >> 6;
    const int lane = tid & 63;

    const float* xb = x + (size_t)b * K * K;

    // Register-cache this lane's w_col fragment (reused by all 16 rows)
    f32x4 wc[4];
#pragma unroll
    for (int jt = 0; jt < 4; ++jt)
        wc[jt] = *reinterpret_cast<const f32x4*>(w_col + jt * 256 + lane * 4);

    // Per-lane column partials for row[b,j] (this wave's 16 rows)
    f32x4 p[4];
#pragma unroll
    for (int jt = 0; jt < 4; ++jt) p[jt] = (f32x4){0.f, 0.f, 0.f, 0.f};

    // 16 per-row dot accumulators — reductions deferred past all loads
    float cacc[16];
    const int rbase = row0 + wave * 16;

#pragma unroll
    for (int k = 0; k < 16; ++k) {
        const int r = rbase + k;
        const float wr = w_row[r];
        const float* xr = xb + (size_t)r * K;
        float c = 0.f;
#pragma unroll
        for (int jt = 0; jt < 4; ++jt) {
            f32x4 xv = __builtin_nontemporal_load(
                reinterpret_cast<const f32x4*>(xr + jt * 256 + lane * 4));
            c += xv.x * wc[jt].x + xv.y * wc[jt].y + xv.z * wc[jt].z + xv.w * wc[jt].w;
            p[jt] += xv * wr;
        }
        cacc[k] = c;
    }

    // Now reduce all 16 row-dots (loads are already all issued/consumed)
#pragma unroll
    for (int k = 0; k < 16; ++k) {
        float c = cacc[k];
#pragma unroll
        for (int off = 32; off; off >>= 1) c += __shfl_xor(c, off);
        if (lane == 0) col_ws[b * K + rbase + k] = c;
    }

    // Combine the 4 waves' column partials in LDS, write this block's partial
    __shared__ float rp[4][K];   // 16 KiB
#pragma unroll
    for (int jt = 0; jt < 4; ++jt)
        *reinterpret_cast<f32x4*>(&rp[wave][jt * 256 + lane * 4]) = p[jt];
    __syncthreads();

    const int j0 = tid * 4;   // thread tid owns columns j0..j0+3
    f32x4 s0 = *reinterpret_cast<const f32x4*>(&rp[0][j0]);
    f32x4 s1 = *reinterpret_cast<const f32x4*>(&rp[1][j0]);
    f32x4 s2 = *reinterpret_cast<const f32x4*>(&rp[2][j0]);
    f32x4 s3 = *reinterpret_cast<const f32x4*>(&rp[3][j0]);
    f32x4 s = (s0 + s1) + (s2 + s3);
    *reinterpret_cast<f32x4*>(&rowpart[(size_t)bid * K + j0]) = s;
}

__global__ __launch_bounds__(256) void
finalize_kernel(const float* __restrict__ col_ws,
                const float* __restrict__ rowpart,
                const float* __restrict__ b_col_p,
                const float* __restrict__ b_row_p,
                float* __restrict__ out)
{
    const int b    = blockIdx.x;
    const int tid  = threadIdx.x;
    const int wave = tid >> 6;
    const int lane = tid & 63;
    const float bc = b_col_p[0];
    const float br = b_row_p[0];

    const int j0 = tid * 4;
    f32x4 c = *reinterpret_cast<const f32x4*>(&col_ws[b * K + j0]);
    f32x4 r = (f32x4){0.f, 0.f, 0.f, 0.f};
#pragma unroll
    for (int pblk = 0; pblk < 16; ++pblk)
        r += *reinterpret_cast<const f32x4*>(
            &rowpart[((size_t)(b * 16 + pblk)) * K + j0]);

    float acc = (c.x + bc) * (r.x + br)
              + (c.y + bc) * (r.y + br)
              + (c.z + bc) * (r.z + br)
              + (c.w + bc) * (r.w + br);
#pragma unroll
    for (int off = 32; off; off >>= 1) acc += __shfl_xor(acc, off);

    __shared__ float red[4];
    if (lane == 0) red[wave] = acc;
    __syncthreads();
    const float S = red[0] + red[1] + red[2] + red[3];

    f32x4 o = (f32x4){S, S, S, S};
    *reinterpret_cast<f32x4*>(&out[b * K + j0]) = o;
}

extern "C" void kernel_launch(void* const* d_in, const int* in_sizes, int n_in,
                              void* d_out, int out_size, void* d_ws, size_t ws_size,
                              hipStream_t stream) {
    const float* x     = (const float*)d_in[0];
    const float* w_col = (const float*)d_in[1];
    const float* b_col = (const float*)d_in[2];
    const float* w_row = (const float*)d_in[3];
    const float* b_row = (const float*)d_in[4];
    float* out = (float*)d_out;

    float* col_ws  = (float*)d_ws;               // NB*K floats
    float* rowpart = col_ws + (size_t)NB * K;    // NB*16*K floats

    rowcol_kernel<<<NB * 16, 256, 0, stream>>>(x, w_col, w_row, col_ws, rowpart);
    finalize_kernel<<<NB, 256, 0, stream>>>(col_ws, rowpart, b_col, b_row, out);
}

// Round 3
// 109.273 us; speedup vs baseline: 1.3404x; 1.0314x over previous
//
#include <hip/hip_runtime.h>
#include <hip/hip_bf16.h>

// Output[b,0,i] = S[b] for all i, where
//   S[b] = sum_j (row[b,j] + b_row) * (col[b,j] + b_col)
//   col[b,i] = sum_j x[b,i,j] * w_col[j]   (weighted row-dot)
//   row[b,j] = sum_i x[b,i,j] * w_row[i]   (weighted column-sum)
//
// Kernel 1: 2048 blocks (B=128 x 16 row-blocks of 64 rows). Streams x once
//   (coalesced float4, nontemporal). Per wave: 16 rows; row-dots reduced via
//   a multiplexed 16-value butterfly (lane L ends holding sum for value L&15,
//   lanes 0..15 issue one coalesced store). Column partials combined in LDS,
//   one partial row written per block (no atomics).
// Kernel 2: 128 blocks. Sums 16 partials per b, dots with col, broadcasts S[b].

#define K 1024
#define NB 128

typedef float f32x4 __attribute__((ext_vector_type(4)));

__global__ __launch_bounds__(256) void
rowcol_kernel(const float* __restrict__ x,
              const float* __restrict__ w_col,
              const float* __restrict__ w_row,
              float* __restrict__ col_ws,     // [NB][K] raw (no bias)
              float* __restrict__ rowpart)    // [NB*16][K] per-block partials
{
    const int bid  = blockIdx.x;
    const int b    = bid >> 4;
    const int rb   = bid & 15;
    const int row0 = rb * 64;
    const int tid  = threadIdx.x;
    const int wave = tid >> 6;
    const int lane = tid & 63;

    const float* xb = x + (size_t)b * K * K;

    // Wave-uniform row base, forced into an SGPR so w_row[] reads scalarize
    // to s_load (scalar cache — no vmem slot, no vmcnt interleave with x).
    const int rbu = __builtin_amdgcn_readfirstlane(row0 + wave * 16);

    // Register-cache this lane's w_col fragment (reused by all 16 rows)
    f32x4 wc[4];
#pragma unroll
    for (int jt = 0; jt < 4; ++jt)
        wc[jt] = *reinterpret_cast<const f32x4*>(w_col + jt * 256 + lane * 4);

    // Per-lane column partials for row[b,j] (this wave's 16 rows)
    f32x4 p[4];
#pragma unroll
    for (int jt = 0; jt < 4; ++jt) p[jt] = (f32x4){0.f, 0.f, 0.f, 0.f};

    float cacc[16];

#pragma unroll
    for (int k = 0; k < 16; ++k) {
        const float wr = w_row[rbu + k];            // s_load, wave-uniform
        const float* xr = xb + (size_t)(rbu + k) * K;
        // Group the 4 NT loads so they issue together
        f32x4 xv0 = __builtin_nontemporal_load(reinterpret_cast<const f32x4*>(xr +   0 + lane * 4));
        f32x4 xv1 = __builtin_nontemporal_load(reinterpret_cast<const f32x4*>(xr + 256 + lane * 4));
        f32x4 xv2 = __builtin_nontemporal_load(reinterpret_cast<const f32x4*>(xr + 512 + lane * 4));
        f32x4 xv3 = __builtin_nontemporal_load(reinterpret_cast<const f32x4*>(xr + 768 + lane * 4));
        // Row-dot as a 4-wide vector accumulator: 4 independent FMA chains of
        // length 4, horizontal-summed once per row.
        f32x4 c4;
        c4  = xv0 * wc[0];
        c4 += xv1 * wc[1];
        c4 += xv2 * wc[2];
        c4 += xv3 * wc[3];
        p[0] += xv0 * wr;
        p[1] += xv1 * wr;
        p[2] += xv2 * wr;
        p[3] += xv3 * wr;
        cacc[k] = (c4.x + c4.y) + (c4.z + c4.w);
    }

    // Multiplexed butterfly reduction of 16 values over 64 lanes.
    // After strides 1,2,4,8: v[0] in lane L holds value (L&15) summed over
    // its 16-lane group; strides 16,32 complete the 64-lane sum.
#pragma unroll
    for (int lvl = 0; lvl < 4; ++lvl) {
        const int s = 1 << lvl;
        const int n = 16 >> (lvl + 1);
#pragma unroll
        for (int m = 0; m < n; ++m) {
            float a = cacc[2 * m]     + __shfl_xor(cacc[2 * m],     s);
            float bb = cacc[2 * m + 1] + __shfl_xor(cacc[2 * m + 1], s);
            cacc[m] = (lane & s) ? bb : a;
        }
    }
    float r = cacc[0];
    r += __shfl_xor(r, 16);
    r += __shfl_xor(r, 32);
    if (lane < 16) col_ws[b * K + rbu + lane] = r;   // one coalesced 64B store

    // Combine the 4 waves' column partials in LDS, write this block's partial
    __shared__ float rp[4][K];   // 16 KiB
#pragma unroll
    for (int jt = 0; jt < 4; ++jt)
        *reinterpret_cast<f32x4*>(&rp[wave][jt * 256 + lane * 4]) = p[jt];
    __syncthreads();

    const int j0 = tid * 4;   // thread tid owns columns j0..j0+3
    f32x4 s0 = *reinterpret_cast<const f32x4*>(&rp[0][j0]);
    f32x4 s1 = *reinterpret_cast<const f32x4*>(&rp[1][j0]);
    f32x4 s2 = *reinterpret_cast<const f32x4*>(&rp[2][j0]);
    f32x4 s3 = *reinterpret_cast<const f32x4*>(&rp[3][j0]);
    f32x4 s = (s0 + s1) + (s2 + s3);
    *reinterpret_cast<f32x4*>(&rowpart[(size_t)bid * K + j0]) = s;
}

__global__ __launch_bounds__(256) void
finalize_kernel(const float* __restrict__ col_ws,
                const float* __restrict__ rowpart,
                const float* __restrict__ b_col_p,
                const float* __restrict__ b_row_p,
                float* __restrict__ out)
{
    const int b    = blockIdx.x;
    const int tid  = threadIdx.x;
    const int wave = tid >> 6;
    const int lane = tid & 63;
    const float bc = b_col_p[0];
    const float br = b_row_p[0];

    const int j0 = tid * 4;
    f32x4 c = *reinterpret_cast<const f32x4*>(&col_ws[b * K + j0]);
    f32x4 r = (f32x4){0.f, 0.f, 0.f, 0.f};
#pragma unroll
    for (int pblk = 0; pblk < 16; ++pblk)
        r += *reinterpret_cast<const f32x4*>(
            &rowpart[((size_t)(b * 16 + pblk)) * K + j0]);

    float acc = (c.x + bc) * (r.x + br)
              + (c.y + bc) * (r.y + br)
              + (c.z + bc) * (r.z + br)
              + (c.w + bc) * (r.w + br);
#pragma unroll
    for (int off = 32; off; off >>= 1) acc += __shfl_xor(acc, off);

    __shared__ float red[4];
    if (lane == 0) red[wave] = acc;
    __syncthreads();
    const float S = red[0] + red[1] + red[2] + red[3];

    f32x4 o = (f32x4){S, S, S, S};
    *reinterpret_cast<f32x4*>(&out[b * K + j0]) = o;
}

extern "C" void kernel_launch(void* const* d_in, const int* in_sizes, int n_in,
                              void* d_out, int out_size, void* d_ws, size_t ws_size,
                              hipStream_t stream) {
    const float* x     = (const float*)d_in[0];
    const float* w_col = (const float*)d_in[1];
    const float* b_col = (const float*)d_in[2];
    const float* w_row = (const float*)d_in[3];
    const float* b_row = (const float*)d_in[4];
    float* out = (float*)d_out;

    float* col_ws  = (float*)d_ws;               // NB*K floats
    float* rowpart = col_ws + (size_t)NB * K;    // NB*16*K floats

    rowcol_kernel<<<NB * 16, 256, 0, stream>>>(x, w_col, w_row, col_ws, rowpart);
    finalize_kernel<<<NB, 256, 0, stream>>>(col_ws, rowpart, b_col, b_row, out);
}